// Round 1
// baseline (860.958 us; speedup 1.0000x reference)
//
#include <hip/hip_runtime.h>
#include <hip/hip_bf16.h>

// MLA prefill: B=4 S=1024 H=32 NOPE=128 ROPE=64 VDIM=128 Q_LORA=1536 KV_LORA=512
// Pipeline: f32->bf16 converts; q-proj GEMM (epilogue: *SCALE + RoPE -> q_full);
// kv-proj GEMM (epilogue: k_nope -> k_full, v -> v^T); k_pe RoPE broadcast;
// causal flash attention (bf16 MFMA 16x16x32, fp32 accum).

typedef __attribute__((ext_vector_type(8))) short s8v;
typedef __attribute__((ext_vector_type(4))) short s4v;
typedef __attribute__((ext_vector_type(4))) float f4v;

#define B_ 4
#define S_ 1024
#define H_ 32
#define SCALE_ 0.07216878364870322992f  // 1/sqrt(192)

__device__ __forceinline__ short f2bf(float f) {
  unsigned u = __builtin_bit_cast(unsigned, f);
  unsigned r = (u + 0x7FFFu + ((u >> 16) & 1u)) >> 16;
  return (short)(unsigned short)r;
}

// ---------------- fp32 -> bf16 convert (vectorized x4) ----------------
__global__ __launch_bounds__(256) void convert_f32_bf16(const float* __restrict__ src,
                                                        short* __restrict__ dst, int n4) {
  int i = blockIdx.x * 256 + threadIdx.x;
  if (i >= n4) return;
  float4 v = reinterpret_cast<const float4*>(src)[i];
  s4v o;
  o[0] = f2bf(v.x); o[1] = f2bf(v.y); o[2] = f2bf(v.z); o[3] = f2bf(v.w);
  reinterpret_cast<s4v*>(dst)[i] = o;
}

// ---------------- GEMM 1: q = Q @ WUQ^T, epilogue scale+rope -> q_full ----------------
// A: [4096][1536] bf16, Bt: [6144][1536] bf16, out q_full: [B][H][S][192] bf16
__global__ __launch_bounds__(256) void gemm_q_kernel(
    const short* __restrict__ A, const short* __restrict__ Bt,
    const float* __restrict__ cosb, const float* __restrict__ sinb,
    short* __restrict__ qfull) {
  constexpr int K = 1536;
  __shared__ short sA[128 * 40];  // rows padded 32->40 shorts (2-way bank alias = free)
  __shared__ short sB[128 * 40];
  const int tid = threadIdx.x;
  const int m0 = blockIdx.x * 128;
  const int n0 = blockIdx.y * 128;
  const int w = tid >> 6, l = tid & 63;
  const int l15 = l & 15, lg = l >> 4;
  const int wr = (w >> 1) * 64, wc = (w & 1) * 64;
  f4v acc[4][4] = {};
  const int r0 = tid >> 2;            // staging row for chunk tid
  const int c0 = (tid & 3) * 8;       // staging col (shorts)
  const int r1 = r0 + 64;             // second chunk

  for (int kk = 0; kk < K; kk += 32) {
    uint4 a0 = *reinterpret_cast<const uint4*>(&A[(size_t)(m0 + r0) * K + kk + c0]);
    uint4 a1 = *reinterpret_cast<const uint4*>(&A[(size_t)(m0 + r1) * K + kk + c0]);
    uint4 b0 = *reinterpret_cast<const uint4*>(&Bt[(size_t)(n0 + r0) * K + kk + c0]);
    uint4 b1 = *reinterpret_cast<const uint4*>(&Bt[(size_t)(n0 + r1) * K + kk + c0]);
    __syncthreads();  // previous iteration's LDS reads done
    *reinterpret_cast<uint4*>(&sA[r0 * 40 + c0]) = a0;
    *reinterpret_cast<uint4*>(&sA[r1 * 40 + c0]) = a1;
    *reinterpret_cast<uint4*>(&sB[r0 * 40 + c0]) = b0;
    *reinterpret_cast<uint4*>(&sB[r1 * 40 + c0]) = b1;
    __syncthreads();
    s8v af[4], bfv[4];
#pragma unroll
    for (int x = 0; x < 4; ++x) {
      af[x]  = *reinterpret_cast<const s8v*>(&sA[(wr + x * 16 + l15) * 40 + lg * 8]);
      bfv[x] = *reinterpret_cast<const s8v*>(&sB[(wc + x * 16 + l15) * 40 + lg * 8]);
    }
#pragma unroll
    for (int i = 0; i < 4; ++i)
#pragma unroll
      for (int j = 0; j < 4; ++j)
        acc[i][j] = __builtin_amdgcn_mfma_f32_16x16x32_bf16(af[i], bfv[j], acc[i][j], 0, 0, 0);
  }

  // epilogue: C/D layout col=l&15, row=(l>>4)*4+reg (m89/m91-verified)
#pragma unroll
  for (int j = 0; j < 4; ++j) {
    const int colb = n0 + wc + j * 16;   // fragment base col (uniform)
    const int e0 = colb % 192;           // 192 = 12*16: no head crossing in a fragment
    const int h = colb / 192;
    const int e = e0 + l15;
    const bool is_pe = (e0 >= 128);
#pragma unroll
    for (int i = 0; i < 4; ++i) {
#pragma unroll
      for (int r = 0; r < 4; ++r) {
        const int row = m0 + wr + i * 16 + lg * 4 + r;  // flattened pos = b*1024+s
        const int b = row >> 10, s = row & 1023;
        const size_t base = ((size_t)(b * H_ + h) * S_ + s) * 192;
        float val = acc[i][j][r] * SCALE_;
        if (!is_pe) {
          qfull[base + e] = f2bf(val);
        } else {
          // rope pair: even lane holds x[2p], odd lane x[2p+1] (same p)
          float other = __shfl_xor(val, 1, 64);
          int p = (e - 128) >> 1;
          float cv = cosb[(size_t)row * 64 + p];
          float sv = sinb[(size_t)row * 64 + p];
          float o = ((l & 1) == 0) ? (val * cv - other * sv) : (val * cv + other * sv);
          int ep = ((l & 1) == 0) ? (128 + p) : (160 + p);
          qfull[base + ep] = f2bf(o);
        }
      }
    }
  }
}

// ---------------- GEMM 2: kvu = KV @ WUKV^T -> k_nope (k_full), v (transposed) ----------------
// A: [4096][512], Bt: [8192][512]; k_full: [B][H][S][192]; vt: [B][H][128][S]
__global__ __launch_bounds__(256) void gemm_kv_kernel(
    const short* __restrict__ A, const short* __restrict__ Bt,
    short* __restrict__ kfull, short* __restrict__ vt) {
  constexpr int K = 512;
  __shared__ short sA[128 * 40];
  __shared__ short sB[128 * 40];
  const int tid = threadIdx.x;
  const int m0 = blockIdx.x * 128;
  const int n0 = blockIdx.y * 128;
  const int w = tid >> 6, l = tid & 63;
  const int l15 = l & 15, lg = l >> 4;
  const int wr = (w >> 1) * 64, wc = (w & 1) * 64;
  f4v acc[4][4] = {};
  const int r0 = tid >> 2;
  const int c0 = (tid & 3) * 8;
  const int r1 = r0 + 64;

  for (int kk = 0; kk < K; kk += 32) {
    uint4 a0 = *reinterpret_cast<const uint4*>(&A[(size_t)(m0 + r0) * K + kk + c0]);
    uint4 a1 = *reinterpret_cast<const uint4*>(&A[(size_t)(m0 + r1) * K + kk + c0]);
    uint4 b0 = *reinterpret_cast<const uint4*>(&Bt[(size_t)(n0 + r0) * K + kk + c0]);
    uint4 b1 = *reinterpret_cast<const uint4*>(&Bt[(size_t)(n0 + r1) * K + kk + c0]);
    __syncthreads();
    *reinterpret_cast<uint4*>(&sA[r0 * 40 + c0]) = a0;
    *reinterpret_cast<uint4*>(&sA[r1 * 40 + c0]) = a1;
    *reinterpret_cast<uint4*>(&sB[r0 * 40 + c0]) = b0;
    *reinterpret_cast<uint4*>(&sB[r1 * 40 + c0]) = b1;
    __syncthreads();
    s8v af[4], bfv[4];
#pragma unroll
    for (int x = 0; x < 4; ++x) {
      af[x]  = *reinterpret_cast<const s8v*>(&sA[(wr + x * 16 + l15) * 40 + lg * 8]);
      bfv[x] = *reinterpret_cast<const s8v*>(&sB[(wc + x * 16 + l15) * 40 + lg * 8]);
    }
#pragma unroll
    for (int i = 0; i < 4; ++i)
#pragma unroll
      for (int j = 0; j < 4; ++j)
        acc[i][j] = __builtin_amdgcn_mfma_f32_16x16x32_bf16(af[i], bfv[j], acc[i][j], 0, 0, 0);
  }

#pragma unroll
  for (int j = 0; j < 4; ++j) {
    const int colb = n0 + wc + j * 16;
    const int e0 = colb % 256;           // 256 = 16*16: no head crossing
    const int h = colb / 256;
    const int e = e0 + l15;
    const bool is_v = (e0 >= 128);
#pragma unroll
    for (int i = 0; i < 4; ++i) {
#pragma unroll
      for (int r = 0; r < 4; ++r) {
        const int row = m0 + wr + i * 16 + lg * 4 + r;
        const int b = row >> 10, s = row & 1023;
        float val = acc[i][j][r];
        if (!is_v) {
          kfull[((size_t)(b * H_ + h) * S_ + s) * 192 + e] = f2bf(val);
        } else {
          vt[((size_t)(b * H_ + h) * 128 + (e - 128)) * S_ + s] = f2bf(val);
        }
      }
    }
  }
}

// ---------------- k_pe: rope(PE) broadcast to all heads ----------------
__global__ __launch_bounds__(64) void kpe_kernel(const float* __restrict__ PE,
                                                 const float* __restrict__ cosb,
                                                 const float* __restrict__ sinb,
                                                 short* __restrict__ kfull) {
  const int pos = blockIdx.x;           // 0..4095
  const int t = threadIdx.x;            // 0..63
  const int p = t & 31;
  float x0 = PE[(size_t)pos * 64 + 2 * p];
  float x1 = PE[(size_t)pos * 64 + 2 * p + 1];
  float cv = cosb[(size_t)pos * 64 + p];
  float sv = sinb[(size_t)pos * 64 + p];
  float o = (t < 32) ? (x0 * cv - x1 * sv) : (x1 * cv + x0 * sv);
  short ob = f2bf(o);
  const int b = pos >> 10, s = pos & 1023;
#pragma unroll
  for (int h = 0; h < H_; ++h)
    kfull[(((size_t)b * H_ + h) * S_ + s) * 192 + 128 + t] = ob;
}

// ---------------- causal flash attention ----------------
// q_full/k_full: [B*H][S][192] bf16 (q pre-scaled); vt: [B*H][128][S] bf16
// out: [B][S][H][128] f32. Block = 64 q-rows (4 waves x 16), KV tile = 32.
__global__ __launch_bounds__(256) void attn_kernel(
    const short* __restrict__ qfull, const short* __restrict__ kfull,
    const short* __restrict__ vt, float* __restrict__ out) {
  const int bh = blockIdx.x >> 4;       // b*32+h
  const int qb = blockIdx.x & 15;
  const int b = bh >> 5, h = bh & 31;
  const int tid = threadIdx.x;
  const int w = tid >> 6, l = tid & 63;
  const int l15 = l & 15, lg = l >> 4;
  const int q0 = qb * 64 + w * 16;      // this wave's 16 q-rows
  const short* Qh = qfull + (size_t)bh * S_ * 192;
  const short* Kh = kfull + (size_t)bh * S_ * 192;
  const short* Vh = vt + (size_t)bh * 128 * S_;
  __shared__ short lds_p[4][16][40];    // padded P transpose buffer, per wave

  s8v qfr[6];
#pragma unroll
  for (int kc = 0; kc < 6; ++kc)
    qfr[kc] = *reinterpret_cast<const s8v*>(&Qh[(size_t)(q0 + l15) * 192 + kc * 32 + lg * 8]);

  f4v acc[8] = {};
  float m[4], lsum[4];
#pragma unroll
  for (int r = 0; r < 4; ++r) { m[r] = -__builtin_inff(); lsum[r] = 0.f; }

  const int ntiles = (qb + 1) * 2;      // kv covers [0, q0_block+64)
  for (int kt = 0; kt < ntiles; ++kt) {
    const int k0 = kt * 32;
    f4v s0 = {0.f, 0.f, 0.f, 0.f}, s1 = {0.f, 0.f, 0.f, 0.f};
#pragma unroll
    for (int kc = 0; kc < 6; ++kc) {
      s8v kf = *reinterpret_cast<const s8v*>(&Kh[(size_t)(k0 + l15) * 192 + kc * 32 + lg * 8]);
      s0 = __builtin_amdgcn_mfma_f32_16x16x32_bf16(qfr[kc], kf, s0, 0, 0, 0);
    }
#pragma unroll
    for (int kc = 0; kc < 6; ++kc) {
      s8v kf = *reinterpret_cast<const s8v*>(&Kh[(size_t)(k0 + 16 + l15) * 192 + kc * 32 + lg * 8]);
      s1 = __builtin_amdgcn_mfma_f32_16x16x32_bf16(qfr[kc], kf, s1, 0, 0, 0);
    }
    // causal mask: D row = q row (lg*4+r), D col = kv col (l15)
#pragma unroll
    for (int r = 0; r < 4; ++r) {
      const int ia = q0 + lg * 4 + r;
      s0[r] = (k0 + l15 > ia) ? -1e30f : s0[r];
      s1[r] = (k0 + 16 + l15 > ia) ? -1e30f : s1[r];
    }
    // online softmax (rows replicated across the 16 lanes sharing lg)
    float tm[4], cf[4], rs[4];
#pragma unroll
    for (int r = 0; r < 4; ++r) tm[r] = fmaxf(s0[r], s1[r]);
#pragma unroll
    for (int msk = 1; msk <= 8; msk <<= 1)
#pragma unroll
      for (int r = 0; r < 4; ++r) tm[r] = fmaxf(tm[r], __shfl_xor(tm[r], msk, 64));
#pragma unroll
    for (int r = 0; r < 4; ++r) {
      float mn = fmaxf(m[r], tm[r]);
      cf[r] = __expf(m[r] - mn);
      m[r] = mn;
      s0[r] = __expf(s0[r] - mn);
      s1[r] = __expf(s1[r] - mn);
      rs[r] = s0[r] + s1[r];
    }
#pragma unroll
    for (int msk = 1; msk <= 8; msk <<= 1)
#pragma unroll
      for (int r = 0; r < 4; ++r) rs[r] += __shfl_xor(rs[r], msk, 64);
#pragma unroll
    for (int r = 0; r < 4; ++r) lsum[r] = lsum[r] * cf[r] + rs[r];
#pragma unroll
    for (int dt = 0; dt < 8; ++dt)
#pragma unroll
      for (int r = 0; r < 4; ++r) acc[dt][r] *= cf[r];
    // P -> LDS (transpose D layout -> A layout)
#pragma unroll
    for (int r = 0; r < 4; ++r) {
      lds_p[w][lg * 4 + r][l15] = f2bf(s0[r]);
      lds_p[w][lg * 4 + r][16 + l15] = f2bf(s1[r]);
    }
    __syncthreads();
    s8v pa = *reinterpret_cast<const s8v*>(&lds_p[w][l15][lg * 8]);
#pragma unroll
    for (int dt = 0; dt < 8; ++dt) {
      s8v vf = *reinterpret_cast<const s8v*>(&Vh[(size_t)(dt * 16 + l15) * S_ + k0 + lg * 8]);
      acc[dt] = __builtin_amdgcn_mfma_f32_16x16x32_bf16(pa, vf, acc[dt], 0, 0, 0);
    }
    __syncthreads();  // protect lds_p for next tile
  }
  // epilogue
  float inv[4];
#pragma unroll
  for (int r = 0; r < 4; ++r) inv[r] = 1.0f / lsum[r];
#pragma unroll
  for (int dt = 0; dt < 8; ++dt)
#pragma unroll
    for (int r = 0; r < 4; ++r) {
      const int row = q0 + lg * 4 + r;
      out[(((size_t)b * S_ + row) * H_ + h) * 128 + dt * 16 + l15] = acc[dt][r] * inv[r];
    }
}

// ---------------- launch ----------------
extern "C" void kernel_launch(void* const* d_in, const int* in_sizes, int n_in,
                              void* d_out, int out_size, void* d_ws, size_t ws_size,
                              hipStream_t stream) {
  const float* Q    = (const float*)d_in[0];
  const float* KV   = (const float*)d_in[1];
  const float* PE   = (const float*)d_in[2];
  const float* WUQ  = (const float*)d_in[3];
  const float* WUKV = (const float*)d_in[4];
  const float* cosb = (const float*)d_in[5];
  const float* sinb = (const float*)d_in[6];
  float* out = (float*)d_out;
  char* ws = (char*)d_ws;

  short* Qb    = (short*)(ws);                   // 4096*1536*2  = 12,582,912
  short* Wq    = (short*)(ws + 12582912);        // 6144*1536*2  = 18,874,368
  short* KVb   = (short*)(ws + 31457280);        // 4096*512*2   =  4,194,304
  short* Wkv   = (short*)(ws + 35651584);        // 8192*512*2   =  8,388,608
  short* qfull = (short*)(ws + 44040192);        // 4*32*1024*192*2 = 50,331,648
  short* kfull = (short*)(ws + 94371840);        // 50,331,648
  short* vtb   = (short*)(ws + 144703488);       // 4*32*128*1024*2 = 33,554,432 (end 178,257,920)

  convert_f32_bf16<<<6144, 256, 0, stream>>>(Q, Qb, 1572864);
  convert_f32_bf16<<<9216, 256, 0, stream>>>(WUQ, Wq, 2359296);
  convert_f32_bf16<<<2048, 256, 0, stream>>>(KV, KVb, 524288);
  convert_f32_bf16<<<4096, 256, 0, stream>>>(WUKV, Wkv, 1048576);

  gemm_q_kernel<<<dim3(32, 48), 256, 0, stream>>>(Qb, Wq, cosb, sinb, qfull);
  gemm_kv_kernel<<<dim3(32, 64), 256, 0, stream>>>(KVb, Wkv, kfull, vtb);
  kpe_kernel<<<4096, 64, 0, stream>>>(PE, cosb, sinb, kfull);

  attn_kernel<<<2048, 256, 0, stream>>>(qfull, kfull, vtb, out);
}

// Round 2
// 364.655 us; speedup vs baseline: 2.3610x; 2.3610x over previous
//
#include <hip/hip_runtime.h>
#include <hip/hip_bf16.h>

// MLA prefill: B=4 S=1024 H=32 NOPE=128 ROPE=64 VDIM=128 Q_LORA=1536 KV_LORA=512
// v2: GEMMs use global_load_lds(16B) staging + XCD swizzle; attention rebuilt:
// swapped QK^T (lane-local softmax rows), swapped PV via shfl relayout (no LDS
// transpose), K tile double-buffered in LDS (XOR-swizzled via pre-swizzled
// global source), V direct from global (L2-fits).

typedef __attribute__((ext_vector_type(8))) short s8v;
typedef __attribute__((ext_vector_type(4))) short s4v;
typedef __attribute__((ext_vector_type(4))) float f4v;

#define B_ 4
#define S_ 1024
#define H_ 32
#define SCALE_ 0.07216878364870322992f  // 1/sqrt(192)

__device__ __forceinline__ short f2bf(float f) {
  unsigned u = __builtin_bit_cast(unsigned, f);
  unsigned r = (u + 0x7FFFu + ((u >> 16) & 1u)) >> 16;
  return (short)(unsigned short)r;
}

// async global->LDS, 16B per lane; LDS dest = wave-uniform base + lane*16
__device__ __forceinline__ void gll16(const void* g, void* l) {
  __builtin_amdgcn_global_load_lds((const __attribute__((address_space(1))) void*)g,
                                   (__attribute__((address_space(3))) void*)l, 16, 0, 0);
}

// ---------------- fp32 -> bf16 convert (vectorized x4) ----------------
__global__ __launch_bounds__(256) void convert_f32_bf16(const float* __restrict__ src,
                                                        short* __restrict__ dst, int n4) {
  int i = blockIdx.x * 256 + threadIdx.x;
  if (i >= n4) return;
  float4 v = reinterpret_cast<const float4*>(src)[i];
  s4v o;
  o[0] = f2bf(v.x); o[1] = f2bf(v.y); o[2] = f2bf(v.z); o[3] = f2bf(v.w);
  reinterpret_cast<s4v*>(dst)[i] = o;
}

// ---------------- GEMM 1: q = Q @ WUQ^T, epilogue scale+rope -> q_full ----------------
// A: [4096][1536] bf16, Bt: [6144][1536] bf16, out q_full: [B][H][S][192] bf16
__global__ __launch_bounds__(256) void gemm_q_kernel(
    const short* __restrict__ A, const short* __restrict__ Bt,
    const float* __restrict__ cosb, const float* __restrict__ sinb,
    short* __restrict__ qfull) {
  constexpr int K = 1536;
  __shared__ short sA[128 * 32];
  __shared__ short sB[128 * 32];
  const int id = blockIdx.x;                    // 1536 blocks, XCD-swizzled
  const int swz = (id & 7) * 192 + (id >> 3);
  const int m0 = (swz & 31) * 128;
  const int n0 = (swz >> 5) * 128;
  const int tid = threadIdx.x;
  const int w = tid >> 6, l = tid & 63;
  const int l15 = l & 15, lg = l >> 4;
  const int wr = (w >> 1) * 64, wc = (w & 1) * 64;
  f4v acc[4][4] = {};
  // staging: wave w covers rows [w*32, w*32+32) of both tiles (2 segs each)
  const int srow = w * 32 + (l >> 2);
  const int scb = (l & 3) * 16;
  const char* gA0 = (const char*)A + ((size_t)(m0 + srow) * K) * 2 + scb;
  const char* gA1 = gA0 + (size_t)16 * K * 2;
  const char* gB0 = (const char*)Bt + ((size_t)(n0 + srow) * K) * 2 + scb;
  const char* gB1 = gB0 + (size_t)16 * K * 2;
  char* lA0 = (char*)sA + (2 * w) * 1024;
  char* lB0 = (char*)sB + (2 * w) * 1024;

  for (int kk = 0; kk < K; kk += 32) {
    __syncthreads();                 // previous iteration's LDS reads done
    gll16(gA0 + kk * 2, lA0);
    gll16(gA1 + kk * 2, lA0 + 1024);
    gll16(gB0 + kk * 2, lB0);
    gll16(gB1 + kk * 2, lB0 + 1024);
    __syncthreads();                 // vmcnt(0) drain -> tile visible
    s8v af[4], bfv[4];
#pragma unroll
    for (int x = 0; x < 4; ++x) {
      af[x]  = *reinterpret_cast<const s8v*>((const char*)sA + (wr + x * 16 + l15) * 64 + lg * 16);
      bfv[x] = *reinterpret_cast<const s8v*>((const char*)sB + (wc + x * 16 + l15) * 64 + lg * 16);
    }
#pragma unroll
    for (int i = 0; i < 4; ++i)
#pragma unroll
      for (int j = 0; j < 4; ++j)
        acc[i][j] = __builtin_amdgcn_mfma_f32_16x16x32_bf16(af[i], bfv[j], acc[i][j], 0, 0, 0);
  }

  // epilogue: C/D layout col=l&15, row=(l>>4)*4+reg
#pragma unroll
  for (int j = 0; j < 4; ++j) {
    const int colb = n0 + wc + j * 16;   // 192 = 12*16: no head crossing in a fragment
    const int e0 = colb % 192;
    const int h = colb / 192;
    const int e = e0 + l15;
    const bool is_pe = (e0 >= 128);
#pragma unroll
    for (int i = 0; i < 4; ++i) {
#pragma unroll
      for (int r = 0; r < 4; ++r) {
        const int row = m0 + wr + i * 16 + lg * 4 + r;  // flattened pos = b*1024+s
        const int b = row >> 10, s = row & 1023;
        const size_t base = ((size_t)(b * H_ + h) * S_ + s) * 192;
        float val = acc[i][j][r] * SCALE_;
        if (!is_pe) {
          qfull[base + e] = f2bf(val);
        } else {
          float other = __shfl_xor(val, 1, 64);
          int p = (e - 128) >> 1;
          float cv = cosb[(size_t)row * 64 + p];
          float sv = sinb[(size_t)row * 64 + p];
          float o = ((l & 1) == 0) ? (val * cv - other * sv) : (val * cv + other * sv);
          int ep = ((l & 1) == 0) ? (128 + p) : (160 + p);
          qfull[base + ep] = f2bf(o);
        }
      }
    }
  }
}

// ---------------- GEMM 2: kvu = KV @ WUKV^T -> k_nope (k_full), v (transposed) ----------------
// A: [4096][512], Bt: [8192][512]; k_full: [B][H][S][192]; vt: [B][H][128][S]
__global__ __launch_bounds__(256) void gemm_kv_kernel(
    const short* __restrict__ A, const short* __restrict__ Bt,
    short* __restrict__ kfull, short* __restrict__ vt) {
  constexpr int K = 512;
  __shared__ short sA[128 * 32];
  __shared__ short sB[128 * 32];
  const int id = blockIdx.x;                    // 2048 blocks, XCD-swizzled
  const int swz = (id & 7) * 256 + (id >> 3);
  const int m0 = (swz & 31) * 128;
  const int n0 = (swz >> 5) * 128;
  const int tid = threadIdx.x;
  const int w = tid >> 6, l = tid & 63;
  const int l15 = l & 15, lg = l >> 4;
  const int wr = (w >> 1) * 64, wc = (w & 1) * 64;
  f4v acc[4][4] = {};
  const int srow = w * 32 + (l >> 2);
  const int scb = (l & 3) * 16;
  const char* gA0 = (const char*)A + ((size_t)(m0 + srow) * K) * 2 + scb;
  const char* gA1 = gA0 + (size_t)16 * K * 2;
  const char* gB0 = (const char*)Bt + ((size_t)(n0 + srow) * K) * 2 + scb;
  const char* gB1 = gB0 + (size_t)16 * K * 2;
  char* lA0 = (char*)sA + (2 * w) * 1024;
  char* lB0 = (char*)sB + (2 * w) * 1024;

  for (int kk = 0; kk < K; kk += 32) {
    __syncthreads();
    gll16(gA0 + kk * 2, lA0);
    gll16(gA1 + kk * 2, lA0 + 1024);
    gll16(gB0 + kk * 2, lB0);
    gll16(gB1 + kk * 2, lB0 + 1024);
    __syncthreads();
    s8v af[4], bfv[4];
#pragma unroll
    for (int x = 0; x < 4; ++x) {
      af[x]  = *reinterpret_cast<const s8v*>((const char*)sA + (wr + x * 16 + l15) * 64 + lg * 16);
      bfv[x] = *reinterpret_cast<const s8v*>((const char*)sB + (wc + x * 16 + l15) * 64 + lg * 16);
    }
#pragma unroll
    for (int i = 0; i < 4; ++i)
#pragma unroll
      for (int j = 0; j < 4; ++j)
        acc[i][j] = __builtin_amdgcn_mfma_f32_16x16x32_bf16(af[i], bfv[j], acc[i][j], 0, 0, 0);
  }

#pragma unroll
  for (int j = 0; j < 4; ++j) {
    const int colb = n0 + wc + j * 16;
    const int e0 = colb % 256;           // 256 = 16*16: no head crossing
    const int h = colb / 256;
    const int e = e0 + l15;
    const bool is_v = (e0 >= 128);
#pragma unroll
    for (int i = 0; i < 4; ++i) {
#pragma unroll
      for (int r = 0; r < 4; ++r) {
        const int row = m0 + wr + i * 16 + lg * 4 + r;
        const int b = row >> 10, s = row & 1023;
        float val = acc[i][j][r];
        if (!is_v) {
          kfull[((size_t)(b * H_ + h) * S_ + s) * 192 + e] = f2bf(val);
        } else {
          vt[((size_t)(b * H_ + h) * 128 + (e - 128)) * S_ + s] = f2bf(val);
        }
      }
    }
  }
}

// ---------------- k_pe: rope(PE) broadcast to all heads ----------------
__global__ __launch_bounds__(64) void kpe_kernel(const float* __restrict__ PE,
                                                 const float* __restrict__ cosb,
                                                 const float* __restrict__ sinb,
                                                 short* __restrict__ kfull) {
  const int pos = blockIdx.x;           // 0..4095
  const int t = threadIdx.x;            // 0..63
  const int p = t & 31;
  float x0 = PE[(size_t)pos * 64 + 2 * p];
  float x1 = PE[(size_t)pos * 64 + 2 * p + 1];
  float cv = cosb[(size_t)pos * 64 + p];
  float sv = sinb[(size_t)pos * 64 + p];
  float o = (t < 32) ? (x0 * cv - x1 * sv) : (x1 * cv + x0 * sv);
  short ob = f2bf(o);
  const int b = pos >> 10, s = pos & 1023;
#pragma unroll
  for (int h = 0; h < H_; ++h)
    kfull[(((size_t)b * H_ + h) * S_ + s) * 192 + 128 + t] = ob;
}

// ---------------- causal flash attention (v2) ----------------
// q_full/k_full: [B*H][S][192] bf16 (q pre-scaled); vt: [B*H][128][S] bf16
// out: [B][S][H][128] f32. Block = 128 q rows (4 waves x 32), KV tile = 64.
// Swapped QK^T: S^T = mfma(K, Q): lane holds P[q=l&15][kv=k0+T*16+lg*4+r].
// Swapped PV:   O^T = mfma(V^T, P^T): acc D[col=l15=q][row=lg*4+r=d].
__global__ __launch_bounds__(256, 2) void attn_kernel(
    const short* __restrict__ qfull, const short* __restrict__ kfull,
    const short* __restrict__ vt, float* __restrict__ out) {
  __shared__ short sK[2][64 * 192];     // double-buffered K tile, 48 KiB
  const int bid = blockIdx.x;
  const int qb = 7 - (bid >> 7);        // longest blocks first
  const int bh = bid & 127;
  const int b = bh >> 5, h = bh & 31;
  const int tid = threadIdx.x;
  const int w = tid >> 6, l = tid & 63;
  const int l15 = l & 15, lg = l >> 4;
  const short* Qh = qfull + (size_t)bh * (S_ * 192);
  const char*  KhB = (const char*)(kfull + (size_t)bh * (S_ * 192));
  const short* Vh = vt + (size_t)bh * (128 * S_);
  const int qw = qb * 128 + w * 32;     // this wave's q base (32 rows)

  // Q fragments (B-operand: lane l15 = q col, k = kc*32+lg*8..+7)
  s8v qfr[2][6];
#pragma unroll
  for (int mq = 0; mq < 2; ++mq)
#pragma unroll
    for (int kc = 0; kc < 6; ++kc)
      qfr[mq][kc] = *reinterpret_cast<const s8v*>(
          &Qh[(size_t)(qw + mq * 16 + l15) * 192 + kc * 32 + lg * 8]);

  // K staging offsets: LDS linear; source pre-swizzled (c ^ ((row&7)<<4)) so
  // readers at row*384 + (cw ^ swz) get K[row][cw] conflict-free.
  unsigned kOff[6];
#pragma unroll
  for (int c = 0; c < 6; ++c) {
    unsigned o = (unsigned)(w * 6 + c) * 1024u + (unsigned)l * 16u;
    unsigned row = o / 384u;
    unsigned cb = o - row * 384u;
    kOff[c] = row * 384u + (cb ^ ((row & 7u) << 4));
  }

  // prologue: stage tile 0 into buf 0
#pragma unroll
  for (int c = 0; c < 6; ++c)
    gll16(KhB + kOff[c], (char*)(&sK[0][0]) + (w * 6 + c) * 1024);
  __syncthreads();

  f4v acc[8][2] = {};
  float mrun[2] = {-3.0e38f, -3.0e38f};
  float lsum[2] = {0.f, 0.f};
  const int nt = 2 * (qb + 1);
  int cur = 0;
  for (int t = 0; t < nt; ++t) {
    const int k0 = t * 64;
    if (t + 1 < nt) {                   // prefetch next tile into other buffer
      const char* gb = KhB + (size_t)(t + 1) * (64 * 384);
      char* lb = (char*)(&sK[cur ^ 1][0]);
#pragma unroll
      for (int c = 0; c < 6; ++c)
        gll16(gb + kOff[c], lb + (w * 6 + c) * 1024);
    }
    if (k0 <= qw + 31) {                // wave-uniform causal skip
      const char* sKc = (const char*)(&sK[cur][0]);
      f4v s[4][2] = {};
#pragma unroll
      for (int T = 0; T < 4; ++T) {
        const int row = T * 16 + l15;
        const unsigned swz = (unsigned)((row & 7) << 4);
#pragma unroll
        for (int kc = 0; kc < 6; ++kc) {
          s8v kf = *reinterpret_cast<const s8v*>(
              sKc + row * 384 + (unsigned)((kc * 64 + lg * 16) ^ swz));
          s[T][0] = __builtin_amdgcn_mfma_f32_16x16x32_bf16(kf, qfr[0][kc], s[T][0], 0, 0, 0);
          s[T][1] = __builtin_amdgcn_mfma_f32_16x16x32_bf16(kf, qfr[1][kc], s[T][1], 0, 0, 0);
        }
      }
      const bool diag = (t >= 2 * qb);
      unsigned pk[4][2][2];
#pragma unroll
      for (int mq = 0; mq < 2; ++mq) {
        const int qlane = qw + mq * 16 + l15;
        if (diag) {
#pragma unroll
          for (int T = 0; T < 4; ++T)
#pragma unroll
            for (int r = 0; r < 4; ++r)
              if (k0 + T * 16 + lg * 4 + r > qlane) s[T][mq][r] = -1.0e30f;
        }
        float tmax = s[0][mq][0];
#pragma unroll
        for (int T = 0; T < 4; ++T)
#pragma unroll
          for (int r = 0; r < 4; ++r) tmax = fmaxf(tmax, s[T][mq][r]);
        tmax = fmaxf(tmax, __shfl_xor(tmax, 16, 64));
        tmax = fmaxf(tmax, __shfl_xor(tmax, 32, 64));
        const float mnew = fmaxf(mrun[mq], tmax);
        const float cf = __expf(mrun[mq] - mnew);
        mrun[mq] = mnew;
        float rs = 0.f;
#pragma unroll
        for (int T = 0; T < 4; ++T)
#pragma unroll
          for (int r = 0; r < 4; ++r) {
            float e = __expf(s[T][mq][r] - mnew);
            s[T][mq][r] = e;
            rs += e;
          }
        rs += __shfl_xor(rs, 16, 64);
        rs += __shfl_xor(rs, 32, 64);
        lsum[mq] = lsum[mq] * cf + rs;
#pragma unroll
        for (int dt = 0; dt < 8; ++dt)
#pragma unroll
          for (int r = 0; r < 4; ++r) acc[dt][mq][r] *= cf;
#pragma unroll
        for (int T = 0; T < 4; ++T) {
          pk[T][mq][0] = (unsigned)(unsigned short)f2bf(s[T][mq][0]) |
                         ((unsigned)(unsigned short)f2bf(s[T][mq][1]) << 16);
          pk[T][mq][1] = (unsigned)(unsigned short)f2bf(s[T][mq][2]) |
                         ((unsigned)(unsigned short)f2bf(s[T][mq][3]) << 16);
        }
      }
      // PV: B-frag word j2 of chunk c2 = pk[2c2+(lg>>1)][j2&1] from lane
      // l15 + 16*((lg&1)*2 + (j2>>1))  (derived + verified lane mapping)
#pragma unroll
      for (int c2 = 0; c2 < 2; ++c2) {
        union { unsigned u[4]; s8v v; } bb[2];
#pragma unroll
        for (int mq = 0; mq < 2; ++mq)
#pragma unroll
          for (int j2 = 0; j2 < 4; ++j2) {
            int src = l15 + ((l & 16) << 1) + ((j2 & 2) << 3);
            unsigned va = (unsigned)__shfl((int)pk[2 * c2][mq][j2 & 1], src, 64);
            unsigned vb = (unsigned)__shfl((int)pk[2 * c2 + 1][mq][j2 & 1], src, 64);
            bb[mq].u[j2] = (l & 32) ? vb : va;
          }
#pragma unroll
        for (int dt = 0; dt < 8; ++dt) {
          s8v vf = *reinterpret_cast<const s8v*>(
              &Vh[(size_t)(dt * 16 + l15) * S_ + k0 + c2 * 32 + lg * 8]);
          acc[dt][0] = __builtin_amdgcn_mfma_f32_16x16x32_bf16(vf, bb[0].v, acc[dt][0], 0, 0, 0);
          acc[dt][1] = __builtin_amdgcn_mfma_f32_16x16x32_bf16(vf, bb[1].v, acc[dt][1], 0, 0, 0);
        }
      }
    }
    __syncthreads();                    // drains prefetch (vmcnt0) + LDS reads
    cur ^= 1;
  }
  // epilogue: O[q][d], 64B-coalesced float4 stores
#pragma unroll
  for (int mq = 0; mq < 2; ++mq) {
    const float inv = 1.0f / lsum[mq];
    const int q = qw + mq * 16 + l15;
    float* ob = out + (((size_t)b * S_ + q) * H_ + h) * 128 + lg * 4;
#pragma unroll
    for (int dt = 0; dt < 8; ++dt) {
      float4 o4 = { acc[dt][mq][0] * inv, acc[dt][mq][1] * inv,
                    acc[dt][mq][2] * inv, acc[dt][mq][3] * inv };
      *reinterpret_cast<float4*>(ob + dt * 16) = o4;
    }
  }
}

// ---------------- launch ----------------
extern "C" void kernel_launch(void* const* d_in, const int* in_sizes, int n_in,
                              void* d_out, int out_size, void* d_ws, size_t ws_size,
                              hipStream_t stream) {
  const float* Q    = (const float*)d_in[0];
  const float* KV   = (const float*)d_in[1];
  const float* PE   = (const float*)d_in[2];
  const float* WUQ  = (const float*)d_in[3];
  const float* WUKV = (const float*)d_in[4];
  const float* cosb = (const float*)d_in[5];
  const float* sinb = (const float*)d_in[6];
  float* out = (float*)d_out;
  char* ws = (char*)d_ws;

  short* Qb    = (short*)(ws);                   // 4096*1536*2  = 12,582,912
  short* Wq    = (short*)(ws + 12582912);        // 6144*1536*2  = 18,874,368
  short* KVb   = (short*)(ws + 31457280);        // 4096*512*2   =  4,194,304
  short* Wkv   = (short*)(ws + 35651584);        // 8192*512*2   =  8,388,608
  short* qfull = (short*)(ws + 44040192);        // 4*32*1024*192*2 = 50,331,648
  short* kfull = (short*)(ws + 94371840);        // 50,331,648
  short* vtb   = (short*)(ws + 144703488);       // 4*32*128*1024*2 = 33,554,432

  convert_f32_bf16<<<6144, 256, 0, stream>>>(Q, Qb, 1572864);
  convert_f32_bf16<<<9216, 256, 0, stream>>>(WUQ, Wq, 2359296);
  convert_f32_bf16<<<2048, 256, 0, stream>>>(KV, KVb, 524288);
  convert_f32_bf16<<<4096, 256, 0, stream>>>(WUKV, Wkv, 1048576);

  gemm_q_kernel<<<1536, 256, 0, stream>>>(Qb, Wq, cosb, sinb, qfull);
  gemm_kv_kernel<<<2048, 256, 0, stream>>>(KVb, Wkv, kfull, vtb);
  kpe_kernel<<<4096, 64, 0, stream>>>(PE, cosb, sinb, kfull);

  attn_kernel<<<1024, 256, 0, stream>>>(qfull, kfull, vtb, out);
}

// Round 3
// 361.668 us; speedup vs baseline: 2.3805x; 1.0083x over previous
//
#include <hip/hip_runtime.h>
#include <hip/hip_bf16.h>

// MLA prefill: B=4 S=1024 H=32 NOPE=128 ROPE=64 VDIM=128 Q_LORA=1536 KV_LORA=512
// v3: GEMMs converted to 2-phase double-buffered schedule (T3 minimal recipe):
// stage next K-tile via global_load_lds BEFORE compute of current tile, one
// barrier per K-step. Attention/kpe/converts unchanged from v2 (verified).

typedef __attribute__((ext_vector_type(8))) short s8v;
typedef __attribute__((ext_vector_type(4))) short s4v;
typedef __attribute__((ext_vector_type(4))) float f4v;

#define B_ 4
#define S_ 1024
#define H_ 32
#define SCALE_ 0.07216878364870322992f  // 1/sqrt(192)

__device__ __forceinline__ short f2bf(float f) {
  unsigned u = __builtin_bit_cast(unsigned, f);
  unsigned r = (u + 0x7FFFu + ((u >> 16) & 1u)) >> 16;
  return (short)(unsigned short)r;
}

// async global->LDS, 16B per lane; LDS dest = wave-uniform base + lane*16
__device__ __forceinline__ void gll16(const void* g, void* l) {
  __builtin_amdgcn_global_load_lds((const __attribute__((address_space(1))) void*)g,
                                   (__attribute__((address_space(3))) void*)l, 16, 0, 0);
}

// ---------------- fp32 -> bf16 convert (vectorized x4) ----------------
__global__ __launch_bounds__(256) void convert_f32_bf16(const float* __restrict__ src,
                                                        short* __restrict__ dst, int n4) {
  int i = blockIdx.x * 256 + threadIdx.x;
  if (i >= n4) return;
  float4 v = reinterpret_cast<const float4*>(src)[i];
  s4v o;
  o[0] = f2bf(v.x); o[1] = f2bf(v.y); o[2] = f2bf(v.z); o[3] = f2bf(v.w);
  reinterpret_cast<s4v*>(dst)[i] = o;
}

// ---------------- GEMM 1: q = Q @ WUQ^T, epilogue scale+rope -> q_full ----------------
// A: [4096][1536] bf16, Bt: [6144][1536] bf16, out q_full: [B][H][S][192] bf16
__global__ __launch_bounds__(256) void gemm_q_kernel(
    const short* __restrict__ A, const short* __restrict__ Bt,
    const float* __restrict__ cosb, const float* __restrict__ sinb,
    short* __restrict__ qfull) {
  constexpr int K = 1536;
  __shared__ short sA[2][128 * 32];   // 8 KiB per buffer
  __shared__ short sB[2][128 * 32];
  const int id = blockIdx.x;                    // 1536 blocks, XCD-swizzled
  const int swz = (id & 7) * 192 + (id >> 3);
  const int m0 = (swz & 31) * 128;
  const int n0 = (swz >> 5) * 128;
  const int tid = threadIdx.x;
  const int w = tid >> 6, l = tid & 63;
  const int l15 = l & 15, lg = l >> 4;
  const int wr = (w >> 1) * 64, wc = (w & 1) * 64;
  f4v acc[4][4] = {};
  // staging: wave w covers rows [w*32, w*32+32) of both tiles (2 segs each)
  const int srow = w * 32 + (l >> 2);
  const int scb = (l & 3) * 16;
  const char* gA0 = (const char*)A + ((size_t)(m0 + srow) * K) * 2 + scb;
  const char* gA1 = gA0 + (size_t)16 * K * 2;
  const char* gB0 = (const char*)Bt + ((size_t)(n0 + srow) * K) * 2 + scb;
  const char* gB1 = gB0 + (size_t)16 * K * 2;
  const int lOff = (2 * w) * 1024;

  // prologue: stage K-tile 0 into buffer 0
  gll16(gA0, (char*)sA[0] + lOff);
  gll16(gA1, (char*)sA[0] + lOff + 1024);
  gll16(gB0, (char*)sB[0] + lOff);
  gll16(gB1, (char*)sB[0] + lOff + 1024);
  __syncthreads();

  int cur = 0;
  for (int kk = 0; kk < K; kk += 32) {
    if (kk + 32 < K) {                 // stage next tile into other buffer FIRST
      gll16(gA0 + (kk + 32) * 2, (char*)sA[cur ^ 1] + lOff);
      gll16(gA1 + (kk + 32) * 2, (char*)sA[cur ^ 1] + lOff + 1024);
      gll16(gB0 + (kk + 32) * 2, (char*)sB[cur ^ 1] + lOff);
      gll16(gB1 + (kk + 32) * 2, (char*)sB[cur ^ 1] + lOff + 1024);
    }
    s8v af[4], bfv[4];
#pragma unroll
    for (int x = 0; x < 4; ++x) {
      af[x]  = *reinterpret_cast<const s8v*>((const char*)sA[cur] + (wr + x * 16 + l15) * 64 + lg * 16);
      bfv[x] = *reinterpret_cast<const s8v*>((const char*)sB[cur] + (wc + x * 16 + l15) * 64 + lg * 16);
    }
#pragma unroll
    for (int i = 0; i < 4; ++i)
#pragma unroll
      for (int j = 0; j < 4; ++j)
        acc[i][j] = __builtin_amdgcn_mfma_f32_16x16x32_bf16(af[i], bfv[j], acc[i][j], 0, 0, 0);
    __syncthreads();                   // drains prefetch + all LDS reads of cur
    cur ^= 1;
  }

  // epilogue: C/D layout col=l&15, row=(l>>4)*4+reg
#pragma unroll
  for (int j = 0; j < 4; ++j) {
    const int colb = n0 + wc + j * 16;   // 192 = 12*16: no head crossing in a fragment
    const int e0 = colb % 192;
    const int h = colb / 192;
    const int e = e0 + l15;
    const bool is_pe = (e0 >= 128);
#pragma unroll
    for (int i = 0; i < 4; ++i) {
#pragma unroll
      for (int r = 0; r < 4; ++r) {
        const int row = m0 + wr + i * 16 + lg * 4 + r;  // flattened pos = b*1024+s
        const int b = row >> 10, s = row & 1023;
        const size_t base = ((size_t)(b * H_ + h) * S_ + s) * 192;
        float val = acc[i][j][r] * SCALE_;
        if (!is_pe) {
          qfull[base + e] = f2bf(val);
        } else {
          float other = __shfl_xor(val, 1, 64);
          int p = (e - 128) >> 1;
          float cv = cosb[(size_t)row * 64 + p];
          float sv = sinb[(size_t)row * 64 + p];
          float o = ((l & 1) == 0) ? (val * cv - other * sv) : (val * cv + other * sv);
          int ep = ((l & 1) == 0) ? (128 + p) : (160 + p);
          qfull[base + ep] = f2bf(o);
        }
      }
    }
  }
}

// ---------------- GEMM 2: kvu = KV @ WUKV^T -> k_nope (k_full), v (transposed) ----------------
// A: [4096][512], Bt: [8192][512]; k_full: [B][H][S][192]; vt: [B][H][128][S]
__global__ __launch_bounds__(256) void gemm_kv_kernel(
    const short* __restrict__ A, const short* __restrict__ Bt,
    short* __restrict__ kfull, short* __restrict__ vt) {
  constexpr int K = 512;
  __shared__ short sA[2][128 * 32];
  __shared__ short sB[2][128 * 32];
  const int id = blockIdx.x;                    // 2048 blocks, XCD-swizzled
  const int swz = (id & 7) * 256 + (id >> 3);
  const int m0 = (swz & 31) * 128;
  const int n0 = (swz >> 5) * 128;
  const int tid = threadIdx.x;
  const int w = tid >> 6, l = tid & 63;
  const int l15 = l & 15, lg = l >> 4;
  const int wr = (w >> 1) * 64, wc = (w & 1) * 64;
  f4v acc[4][4] = {};
  const int srow = w * 32 + (l >> 2);
  const int scb = (l & 3) * 16;
  const char* gA0 = (const char*)A + ((size_t)(m0 + srow) * K) * 2 + scb;
  const char* gA1 = gA0 + (size_t)16 * K * 2;
  const char* gB0 = (const char*)Bt + ((size_t)(n0 + srow) * K) * 2 + scb;
  const char* gB1 = gB0 + (size_t)16 * K * 2;
  const int lOff = (2 * w) * 1024;

  gll16(gA0, (char*)sA[0] + lOff);
  gll16(gA1, (char*)sA[0] + lOff + 1024);
  gll16(gB0, (char*)sB[0] + lOff);
  gll16(gB1, (char*)sB[0] + lOff + 1024);
  __syncthreads();

  int cur = 0;
  for (int kk = 0; kk < K; kk += 32) {
    if (kk + 32 < K) {
      gll16(gA0 + (kk + 32) * 2, (char*)sA[cur ^ 1] + lOff);
      gll16(gA1 + (kk + 32) * 2, (char*)sA[cur ^ 1] + lOff + 1024);
      gll16(gB0 + (kk + 32) * 2, (char*)sB[cur ^ 1] + lOff);
      gll16(gB1 + (kk + 32) * 2, (char*)sB[cur ^ 1] + lOff + 1024);
    }
    s8v af[4], bfv[4];
#pragma unroll
    for (int x = 0; x < 4; ++x) {
      af[x]  = *reinterpret_cast<const s8v*>((const char*)sA[cur] + (wr + x * 16 + l15) * 64 + lg * 16);
      bfv[x] = *reinterpret_cast<const s8v*>((const char*)sB[cur] + (wc + x * 16 + l15) * 64 + lg * 16);
    }
#pragma unroll
    for (int i = 0; i < 4; ++i)
#pragma unroll
      for (int j = 0; j < 4; ++j)
        acc[i][j] = __builtin_amdgcn_mfma_f32_16x16x32_bf16(af[i], bfv[j], acc[i][j], 0, 0, 0);
    __syncthreads();
    cur ^= 1;
  }

#pragma unroll
  for (int j = 0; j < 4; ++j) {
    const int colb = n0 + wc + j * 16;
    const int e0 = colb % 256;           // 256 = 16*16: no head crossing
    const int h = colb / 256;
    const int e = e0 + l15;
    const bool is_v = (e0 >= 128);
#pragma unroll
    for (int i = 0; i < 4; ++i) {
#pragma unroll
      for (int r = 0; r < 4; ++r) {
        const int row = m0 + wr + i * 16 + lg * 4 + r;
        const int b = row >> 10, s = row & 1023;
        float val = acc[i][j][r];
        if (!is_v) {
          kfull[((size_t)(b * H_ + h) * S_ + s) * 192 + e] = f2bf(val);
        } else {
          vt[((size_t)(b * H_ + h) * 128 + (e - 128)) * S_ + s] = f2bf(val);
        }
      }
    }
  }
}

// ---------------- k_pe: rope(PE) broadcast to all heads ----------------
__global__ __launch_bounds__(64) void kpe_kernel(const float* __restrict__ PE,
                                                 const float* __restrict__ cosb,
                                                 const float* __restrict__ sinb,
                                                 short* __restrict__ kfull) {
  const int pos = blockIdx.x;           // 0..4095
  const int t = threadIdx.x;            // 0..63
  const int p = t & 31;
  float x0 = PE[(size_t)pos * 64 + 2 * p];
  float x1 = PE[(size_t)pos * 64 + 2 * p + 1];
  float cv = cosb[(size_t)pos * 64 + p];
  float sv = sinb[(size_t)pos * 64 + p];
  float o = (t < 32) ? (x0 * cv - x1 * sv) : (x1 * cv + x0 * sv);
  short ob = f2bf(o);
  const int b = pos >> 10, s = pos & 1023;
#pragma unroll
  for (int h = 0; h < H_; ++h)
    kfull[(((size_t)b * H_ + h) * S_ + s) * 192 + 128 + t] = ob;
}

// ---------------- causal flash attention (v2, unchanged) ----------------
// q_full/k_full: [B*H][S][192] bf16 (q pre-scaled); vt: [B*H][128][S] bf16
// out: [B][S][H][128] f32. Block = 128 q rows (4 waves x 32), KV tile = 64.
// Swapped QK^T: S^T = mfma(K, Q): lane holds P[q=l&15][kv=k0+T*16+lg*4+r].
// Swapped PV:   O^T = mfma(V^T, P^T): acc D[col=l15=q][row=lg*4+r=d].
__global__ __launch_bounds__(256, 2) void attn_kernel(
    const short* __restrict__ qfull, const short* __restrict__ kfull,
    const short* __restrict__ vt, float* __restrict__ out) {
  __shared__ short sK[2][64 * 192];     // double-buffered K tile, 48 KiB
  const int bid = blockIdx.x;
  const int qb = 7 - (bid >> 7);        // longest blocks first
  const int bh = bid & 127;
  const int b = bh >> 5, h = bh & 31;
  const int tid = threadIdx.x;
  const int w = tid >> 6, l = tid & 63;
  const int l15 = l & 15, lg = l >> 4;
  const short* Qh = qfull + (size_t)bh * (S_ * 192);
  const char*  KhB = (const char*)(kfull + (size_t)bh * (S_ * 192));
  const short* Vh = vt + (size_t)bh * (128 * S_);
  const int qw = qb * 128 + w * 32;     // this wave's q base (32 rows)

  // Q fragments (B-operand: lane l15 = q col, k = kc*32+lg*8..+7)
  s8v qfr[2][6];
#pragma unroll
  for (int mq = 0; mq < 2; ++mq)
#pragma unroll
    for (int kc = 0; kc < 6; ++kc)
      qfr[mq][kc] = *reinterpret_cast<const s8v*>(
          &Qh[(size_t)(qw + mq * 16 + l15) * 192 + kc * 32 + lg * 8]);

  // K staging offsets: LDS linear; source pre-swizzled (c ^ ((row&7)<<4)) so
  // readers at row*384 + (cw ^ swz) get K[row][cw] conflict-free.
  unsigned kOff[6];
#pragma unroll
  for (int c = 0; c < 6; ++c) {
    unsigned o = (unsigned)(w * 6 + c) * 1024u + (unsigned)l * 16u;
    unsigned row = o / 384u;
    unsigned cb = o - row * 384u;
    kOff[c] = row * 384u + (cb ^ ((row & 7u) << 4));
  }

  // prologue: stage tile 0 into buf 0
#pragma unroll
  for (int c = 0; c < 6; ++c)
    gll16(KhB + kOff[c], (char*)(&sK[0][0]) + (w * 6 + c) * 1024);
  __syncthreads();

  f4v acc[8][2] = {};
  float mrun[2] = {-3.0e38f, -3.0e38f};
  float lsum[2] = {0.f, 0.f};
  const int nt = 2 * (qb + 1);
  int cur = 0;
  for (int t = 0; t < nt; ++t) {
    const int k0 = t * 64;
    if (t + 1 < nt) {                   // prefetch next tile into other buffer
      const char* gb = KhB + (size_t)(t + 1) * (64 * 384);
      char* lb = (char*)(&sK[cur ^ 1][0]);
#pragma unroll
      for (int c = 0; c < 6; ++c)
        gll16(gb + kOff[c], lb + (w * 6 + c) * 1024);
    }
    if (k0 <= qw + 31) {                // wave-uniform causal skip
      const char* sKc = (const char*)(&sK[cur][0]);
      f4v s[4][2] = {};
#pragma unroll
      for (int T = 0; T < 4; ++T) {
        const int row = T * 16 + l15;
        const unsigned swz = (unsigned)((row & 7) << 4);
#pragma unroll
        for (int kc = 0; kc < 6; ++kc) {
          s8v kf = *reinterpret_cast<const s8v*>(
              sKc + row * 384 + (unsigned)((kc * 64 + lg * 16) ^ swz));
          s[T][0] = __builtin_amdgcn_mfma_f32_16x16x32_bf16(kf, qfr[0][kc], s[T][0], 0, 0, 0);
          s[T][1] = __builtin_amdgcn_mfma_f32_16x16x32_bf16(kf, qfr[1][kc], s[T][1], 0, 0, 0);
        }
      }
      const bool diag = (t >= 2 * qb);
      unsigned pk[4][2][2];
#pragma unroll
      for (int mq = 0; mq < 2; ++mq) {
        const int qlane = qw + mq * 16 + l15;
        if (diag) {
#pragma unroll
          for (int T = 0; T < 4; ++T)
#pragma unroll
            for (int r = 0; r < 4; ++r)
              if (k0 + T * 16 + lg * 4 + r > qlane) s[T][mq][r] = -1.0e30f;
        }
        float tmax = s[0][mq][0];
#pragma unroll
        for (int T = 0; T < 4; ++T)
#pragma unroll
          for (int r = 0; r < 4; ++r) tmax = fmaxf(tmax, s[T][mq][r]);
        tmax = fmaxf(tmax, __shfl_xor(tmax, 16, 64));
        tmax = fmaxf(tmax, __shfl_xor(tmax, 32, 64));
        const float mnew = fmaxf(mrun[mq], tmax);
        const float cf = __expf(mrun[mq] - mnew);
        mrun[mq] = mnew;
        float rs = 0.f;
#pragma unroll
        for (int T = 0; T < 4; ++T)
#pragma unroll
          for (int r = 0; r < 4; ++r) {
            float e = __expf(s[T][mq][r] - mnew);
            s[T][mq][r] = e;
            rs += e;
          }
        rs += __shfl_xor(rs, 16, 64);
        rs += __shfl_xor(rs, 32, 64);
        lsum[mq] = lsum[mq] * cf + rs;
#pragma unroll
        for (int dt = 0; dt < 8; ++dt)
#pragma unroll
          for (int r = 0; r < 4; ++r) acc[dt][mq][r] *= cf;
#pragma unroll
        for (int T = 0; T < 4; ++T) {
          pk[T][mq][0] = (unsigned)(unsigned short)f2bf(s[T][mq][0]) |
                         ((unsigned)(unsigned short)f2bf(s[T][mq][1]) << 16);
          pk[T][mq][1] = (unsigned)(unsigned short)f2bf(s[T][mq][2]) |
                         ((unsigned)(unsigned short)f2bf(s[T][mq][3]) << 16);
        }
      }
      // PV: B-frag word j2 of chunk c2 = pk[2c2+(lg>>1)][j2&1] from lane
      // l15 + 16*((lg&1)*2 + (j2>>1))  (derived + verified lane mapping)
#pragma unroll
      for (int c2 = 0; c2 < 2; ++c2) {
        union { unsigned u[4]; s8v v; } bb[2];
#pragma unroll
        for (int mq = 0; mq < 2; ++mq)
#pragma unroll
          for (int j2 = 0; j2 < 4; ++j2) {
            int src = l15 + ((l & 16) << 1) + ((j2 & 2) << 3);
            unsigned va = (unsigned)__shfl((int)pk[2 * c2][mq][j2 & 1], src, 64);
            unsigned vb = (unsigned)__shfl((int)pk[2 * c2 + 1][mq][j2 & 1], src, 64);
            bb[mq].u[j2] = (l & 32) ? vb : va;
          }
#pragma unroll
        for (int dt = 0; dt < 8; ++dt) {
          s8v vf = *reinterpret_cast<const s8v*>(
              &Vh[(size_t)(dt * 16 + l15) * S_ + k0 + c2 * 32 + lg * 8]);
          acc[dt][0] = __builtin_amdgcn_mfma_f32_16x16x32_bf16(vf, bb[0].v, acc[dt][0], 0, 0, 0);
          acc[dt][1] = __builtin_amdgcn_mfma_f32_16x16x32_bf16(vf, bb[1].v, acc[dt][1], 0, 0, 0);
        }
      }
    }
    __syncthreads();                    // drains prefetch (vmcnt0) + LDS reads
    cur ^= 1;
  }
  // epilogue: O[q][d], 64B-coalesced float4 stores
#pragma unroll
  for (int mq = 0; mq < 2; ++mq) {
    const float inv = 1.0f / lsum[mq];
    const int q = qw + mq * 16 + l15;
    float* ob = out + (((size_t)b * S_ + q) * H_ + h) * 128 + lg * 4;
#pragma unroll
    for (int dt = 0; dt < 8; ++dt) {
      float4 o4 = { acc[dt][mq][0] * inv, acc[dt][mq][1] * inv,
                    acc[dt][mq][2] * inv, acc[dt][mq][3] * inv };
      *reinterpret_cast<float4*>(ob + dt * 16) = o4;
    }
  }
}

// ---------------- launch ----------------
extern "C" void kernel_launch(void* const* d_in, const int* in_sizes, int n_in,
                              void* d_out, int out_size, void* d_ws, size_t ws_size,
                              hipStream_t stream) {
  const float* Q    = (const float*)d_in[0];
  const float* KV   = (const float*)d_in[1];
  const float* PE   = (const float*)d_in[2];
  const float* WUQ  = (const float*)d_in[3];
  const float* WUKV = (const float*)d_in[4];
  const float* cosb = (const float*)d_in[5];
  const float* sinb = (const float*)d_in[6];
  float* out = (float*)d_out;
  char* ws = (char*)d_ws;

  short* Qb    = (short*)(ws);                   // 4096*1536*2  = 12,582,912
  short* Wq    = (short*)(ws + 12582912);        // 6144*1536*2  = 18,874,368
  short* KVb   = (short*)(ws + 31457280);        // 4096*512*2   =  4,194,304
  short* Wkv   = (short*)(ws + 35651584);        // 8192*512*2   =  8,388,608
  short* qfull = (short*)(ws + 44040192);        // 4*32*1024*192*2 = 50,331,648
  short* kfull = (short*)(ws + 94371840);        // 50,331,648
  short* vtb   = (short*)(ws + 144703488);       // 4*32*128*1024*2 = 33,554,432

  convert_f32_bf16<<<6144, 256, 0, stream>>>(Q, Qb, 1572864);
  convert_f32_bf16<<<9216, 256, 0, stream>>>(WUQ, Wq, 2359296);
  convert_f32_bf16<<<2048, 256, 0, stream>>>(KV, KVb, 524288);
  convert_f32_bf16<<<4096, 256, 0, stream>>>(WUKV, Wkv, 1048576);

  gemm_q_kernel<<<1536, 256, 0, stream>>>(Qb, Wq, cosb, sinb, qfull);
  gemm_kv_kernel<<<2048, 256, 0, stream>>>(KVb, Wkv, kfull, vtb);
  kpe_kernel<<<4096, 64, 0, stream>>>(PE, cosb, sinb, kfull);

  attn_kernel<<<1024, 256, 0, stream>>>(qfull, kfull, vtb, out);
}

// Round 4
// 344.227 us; speedup vs baseline: 2.5011x; 1.0507x over previous
//
#include <hip/hip_runtime.h>
#include <hip/hip_bf16.h>

// MLA prefill: B=4 S=1024 H=32 NOPE=128 ROPE=64 VDIM=128 Q_LORA=1536 KV_LORA=512
// v4: GEMMs: BK=64 (halves barrier count: 32 MFMA per barrier), LDS tiles
// [128][64] bf16 with XOR slot-swizzle (slot ^= row&7) via pre-swizzled global
// source + swizzled ds_read (conflict-free), double-buffered, stage-ahead,
// one __syncthreads per K-step. Attention/kpe/converts unchanged (verified).

typedef __attribute__((ext_vector_type(8))) short s8v;
typedef __attribute__((ext_vector_type(4))) short s4v;
typedef __attribute__((ext_vector_type(4))) float f4v;

#define B_ 4
#define S_ 1024
#define H_ 32
#define SCALE_ 0.07216878364870322992f  // 1/sqrt(192)

__device__ __forceinline__ short f2bf(float f) {
  unsigned u = __builtin_bit_cast(unsigned, f);
  unsigned r = (u + 0x7FFFu + ((u >> 16) & 1u)) >> 16;
  return (short)(unsigned short)r;
}

// async global->LDS, 16B per lane; LDS dest = wave-uniform base + lane*16
__device__ __forceinline__ void gll16(const void* g, void* l) {
  __builtin_amdgcn_global_load_lds((const __attribute__((address_space(1))) void*)g,
                                   (__attribute__((address_space(3))) void*)l, 16, 0, 0);
}

// ---------------- fp32 -> bf16 convert (vectorized x4) ----------------
__global__ __launch_bounds__(256) void convert_f32_bf16(const float* __restrict__ src,
                                                        short* __restrict__ dst, int n4) {
  int i = blockIdx.x * 256 + threadIdx.x;
  if (i >= n4) return;
  float4 v = reinterpret_cast<const float4*>(src)[i];
  s4v o;
  o[0] = f2bf(v.x); o[1] = f2bf(v.y); o[2] = f2bf(v.z); o[3] = f2bf(v.w);
  reinterpret_cast<s4v*>(dst)[i] = o;
}

// ---------------- GEMM 1: q = Q @ WUQ^T, epilogue scale+rope -> q_full ----------------
// A: [4096][1536] bf16, Bt: [6144][1536] bf16, out q_full: [B][H][S][192] bf16
__global__ __launch_bounds__(256) void gemm_q_kernel(
    const short* __restrict__ A, const short* __restrict__ Bt,
    const float* __restrict__ cosb, const float* __restrict__ sinb,
    short* __restrict__ qfull) {
  constexpr int K = 1536;
  __shared__ short sA[2][128 * 64];   // 16 KiB per buffer, [row][64] bf16
  __shared__ short sB[2][128 * 64];
  const int id = blockIdx.x;                    // 1536 blocks, XCD-swizzled
  const int swz = (id & 7) * 192 + (id >> 3);
  const int m0 = (swz & 31) * 128;
  const int n0 = (swz >> 5) * 128;
  const int tid = threadIdx.x;
  const int w = tid >> 6, l = tid & 63;
  const int l15 = l & 15, lg = l >> 4;
  const int wr = (w >> 1) * 64, wc = (w & 1) * 64;
  f4v acc[4][4] = {};
  // staging: round r4 covers rows 32*r4 + (tid>>3), phys slot tid&7; LDS(row,
  // sp) holds logical col-block sp ^ (row&7)  -> source pre-swizzled.
  const int srow = tid >> 3;           // 0..31
  const int sslot = tid & 7;
  const int swsl = sslot ^ (srow & 7); // logical slot to fetch
  const char* gA = (const char*)A + ((size_t)(m0 + srow) * K + swsl * 8) * 2;
  const char* gB = (const char*)Bt + ((size_t)(n0 + srow) * K + swsl * 8) * 2;
  const int ldst = tid * 16;           // + r4*4096

  // prologue: stage K-tile 0 into buffer 0
#pragma unroll
  for (int r4 = 0; r4 < 4; ++r4) {
    gll16(gA + (size_t)r4 * (32 * K * 2), (char*)sA[0] + r4 * 4096 + ldst);
    gll16(gB + (size_t)r4 * (32 * K * 2), (char*)sB[0] + r4 * 4096 + ldst);
  }

  int cur = 0;
  const int swzA = l15 & 7;            // read-side row&7 (wr, x*16 are mult of 8)
  for (int kk = 0; kk < K; kk += 64) {
    __syncthreads();                   // vmcnt(0)+barrier: tile kk ready, buf^1 free
    if (kk + 64 < K) {
      const char* ga = gA + (size_t)(kk + 64) * 2;
      const char* gb = gB + (size_t)(kk + 64) * 2;
#pragma unroll
      for (int r4 = 0; r4 < 4; ++r4) {
        gll16(ga + (size_t)r4 * (32 * K * 2), (char*)sA[cur ^ 1] + r4 * 4096 + ldst);
        gll16(gb + (size_t)r4 * (32 * K * 2), (char*)sB[cur ^ 1] + r4 * 4096 + ldst);
      }
    }
#pragma unroll
    for (int kc = 0; kc < 2; ++kc) {
      s8v af[4], bfv[4];
#pragma unroll
      for (int x = 0; x < 4; ++x) {
        af[x]  = *reinterpret_cast<const s8v*>(
            (const char*)sA[cur] + (wr + x * 16 + l15) * 128 + (((kc * 4 + lg) ^ swzA) * 16));
        bfv[x] = *reinterpret_cast<const s8v*>(
            (const char*)sB[cur] + (wc + x * 16 + l15) * 128 + (((kc * 4 + lg) ^ swzA) * 16));
      }
#pragma unroll
      for (int i = 0; i < 4; ++i)
#pragma unroll
        for (int j = 0; j < 4; ++j)
          acc[i][j] = __builtin_amdgcn_mfma_f32_16x16x32_bf16(af[i], bfv[j], acc[i][j], 0, 0, 0);
    }
    cur ^= 1;
  }

  // epilogue: C/D layout col=l&15, row=(l>>4)*4+reg
#pragma unroll
  for (int j = 0; j < 4; ++j) {
    const int colb = n0 + wc + j * 16;   // 192 = 12*16: no head crossing in a fragment
    const int e0 = colb % 192;
    const int h = colb / 192;
    const int e = e0 + l15;
    const bool is_pe = (e0 >= 128);
#pragma unroll
    for (int i = 0; i < 4; ++i) {
#pragma unroll
      for (int r = 0; r < 4; ++r) {
        const int row = m0 + wr + i * 16 + lg * 4 + r;  // flattened pos = b*1024+s
        const int b = row >> 10, s = row & 1023;
        const size_t base = ((size_t)(b * H_ + h) * S_ + s) * 192;
        float val = acc[i][j][r] * SCALE_;
        if (!is_pe) {
          qfull[base + e] = f2bf(val);
        } else {
          float other = __shfl_xor(val, 1, 64);
          int p = (e - 128) >> 1;
          float cv = cosb[(size_t)row * 64 + p];
          float sv = sinb[(size_t)row * 64 + p];
          float o = ((l & 1) == 0) ? (val * cv - other * sv) : (val * cv + other * sv);
          int ep = ((l & 1) == 0) ? (128 + p) : (160 + p);
          qfull[base + ep] = f2bf(o);
        }
      }
    }
  }
}

// ---------------- GEMM 2: kvu = KV @ WUKV^T -> k_nope (k_full), v (transposed) ----------------
// A: [4096][512], Bt: [8192][512]; k_full: [B][H][S][192]; vt: [B][H][128][S]
__global__ __launch_bounds__(256) void gemm_kv_kernel(
    const short* __restrict__ A, const short* __restrict__ Bt,
    short* __restrict__ kfull, short* __restrict__ vt) {
  constexpr int K = 512;
  __shared__ short sA[2][128 * 64];
  __shared__ short sB[2][128 * 64];
  const int id = blockIdx.x;                    // 2048 blocks, XCD-swizzled
  const int swz = (id & 7) * 256 + (id >> 3);
  const int m0 = (swz & 31) * 128;
  const int n0 = (swz >> 5) * 128;
  const int tid = threadIdx.x;
  const int w = tid >> 6, l = tid & 63;
  const int l15 = l & 15, lg = l >> 4;
  const int wr = (w >> 1) * 64, wc = (w & 1) * 64;
  f4v acc[4][4] = {};
  const int srow = tid >> 3;
  const int sslot = tid & 7;
  const int swsl = sslot ^ (srow & 7);
  const char* gA = (const char*)A + ((size_t)(m0 + srow) * K + swsl * 8) * 2;
  const char* gB = (const char*)Bt + ((size_t)(n0 + srow) * K + swsl * 8) * 2;
  const int ldst = tid * 16;

#pragma unroll
  for (int r4 = 0; r4 < 4; ++r4) {
    gll16(gA + (size_t)r4 * (32 * K * 2), (char*)sA[0] + r4 * 4096 + ldst);
    gll16(gB + (size_t)r4 * (32 * K * 2), (char*)sB[0] + r4 * 4096 + ldst);
  }

  int cur = 0;
  const int swzA = l15 & 7;
  for (int kk = 0; kk < K; kk += 64) {
    __syncthreads();
    if (kk + 64 < K) {
      const char* ga = gA + (size_t)(kk + 64) * 2;
      const char* gb = gB + (size_t)(kk + 64) * 2;
#pragma unroll
      for (int r4 = 0; r4 < 4; ++r4) {
        gll16(ga + (size_t)r4 * (32 * K * 2), (char*)sA[cur ^ 1] + r4 * 4096 + ldst);
        gll16(gb + (size_t)r4 * (32 * K * 2), (char*)sB[cur ^ 1] + r4 * 4096 + ldst);
      }
    }
#pragma unroll
    for (int kc = 0; kc < 2; ++kc) {
      s8v af[4], bfv[4];
#pragma unroll
      for (int x = 0; x < 4; ++x) {
        af[x]  = *reinterpret_cast<const s8v*>(
            (const char*)sA[cur] + (wr + x * 16 + l15) * 128 + (((kc * 4 + lg) ^ swzA) * 16));
        bfv[x] = *reinterpret_cast<const s8v*>(
            (const char*)sB[cur] + (wc + x * 16 + l15) * 128 + (((kc * 4 + lg) ^ swzA) * 16));
      }
#pragma unroll
      for (int i = 0; i < 4; ++i)
#pragma unroll
        for (int j = 0; j < 4; ++j)
          acc[i][j] = __builtin_amdgcn_mfma_f32_16x16x32_bf16(af[i], bfv[j], acc[i][j], 0, 0, 0);
    }
    cur ^= 1;
  }

#pragma unroll
  for (int j = 0; j < 4; ++j) {
    const int colb = n0 + wc + j * 16;
    const int e0 = colb % 256;           // 256 = 16*16: no head crossing
    const int h = colb / 256;
    const int e = e0 + l15;
    const bool is_v = (e0 >= 128);
#pragma unroll
    for (int i = 0; i < 4; ++i) {
#pragma unroll
      for (int r = 0; r < 4; ++r) {
        const int row = m0 + wr + i * 16 + lg * 4 + r;
        const int b = row >> 10, s = row & 1023;
        float val = acc[i][j][r];
        if (!is_v) {
          kfull[((size_t)(b * H_ + h) * S_ + s) * 192 + e] = f2bf(val);
        } else {
          vt[((size_t)(b * H_ + h) * 128 + (e - 128)) * S_ + s] = f2bf(val);
        }
      }
    }
  }
}

// ---------------- k_pe: rope(PE) broadcast to all heads ----------------
__global__ __launch_bounds__(64) void kpe_kernel(const float* __restrict__ PE,
                                                 const float* __restrict__ cosb,
                                                 const float* __restrict__ sinb,
                                                 short* __restrict__ kfull) {
  const int pos = blockIdx.x;           // 0..4095
  const int t = threadIdx.x;            // 0..63
  const int p = t & 31;
  float x0 = PE[(size_t)pos * 64 + 2 * p];
  float x1 = PE[(size_t)pos * 64 + 2 * p + 1];
  float cv = cosb[(size_t)pos * 64 + p];
  float sv = sinb[(size_t)pos * 64 + p];
  float o = (t < 32) ? (x0 * cv - x1 * sv) : (x1 * cv + x0 * sv);
  short ob = f2bf(o);
  const int b = pos >> 10, s = pos & 1023;
#pragma unroll
  for (int h = 0; h < H_; ++h)
    kfull[(((size_t)b * H_ + h) * S_ + s) * 192 + 128 + t] = ob;
}

// ---------------- causal flash attention (v2, unchanged) ----------------
// q_full/k_full: [B*H][S][192] bf16 (q pre-scaled); vt: [B*H][128][S] bf16
// out: [B][S][H][128] f32. Block = 128 q rows (4 waves x 32), KV tile = 64.
// Swapped QK^T: S^T = mfma(K, Q): lane holds P[q=l&15][kv=k0+T*16+lg*4+r].
// Swapped PV:   O^T = mfma(V^T, P^T): acc D[col=l15=q][row=lg*4+r=d].
__global__ __launch_bounds__(256, 2) void attn_kernel(
    const short* __restrict__ qfull, const short* __restrict__ kfull,
    const short* __restrict__ vt, float* __restrict__ out) {
  __shared__ short sK[2][64 * 192];     // double-buffered K tile, 48 KiB
  const int bid = blockIdx.x;
  const int qb = 7 - (bid >> 7);        // longest blocks first
  const int bh = bid & 127;
  const int b = bh >> 5, h = bh & 31;
  const int tid = threadIdx.x;
  const int w = tid >> 6, l = tid & 63;
  const int l15 = l & 15, lg = l >> 4;
  const short* Qh = qfull + (size_t)bh * (S_ * 192);
  const char*  KhB = (const char*)(kfull + (size_t)bh * (S_ * 192));
  const short* Vh = vt + (size_t)bh * (128 * S_);
  const int qw = qb * 128 + w * 32;     // this wave's q base (32 rows)

  // Q fragments (B-operand: lane l15 = q col, k = kc*32+lg*8..+7)
  s8v qfr[2][6];
#pragma unroll
  for (int mq = 0; mq < 2; ++mq)
#pragma unroll
    for (int kc = 0; kc < 6; ++kc)
      qfr[mq][kc] = *reinterpret_cast<const s8v*>(
          &Qh[(size_t)(qw + mq * 16 + l15) * 192 + kc * 32 + lg * 8]);

  // K staging offsets: LDS linear; source pre-swizzled (c ^ ((row&7)<<4)) so
  // readers at row*384 + (cw ^ swz) get K[row][cw] conflict-free.
  unsigned kOff[6];
#pragma unroll
  for (int c = 0; c < 6; ++c) {
    unsigned o = (unsigned)(w * 6 + c) * 1024u + (unsigned)l * 16u;
    unsigned row = o / 384u;
    unsigned cb = o - row * 384u;
    kOff[c] = row * 384u + (cb ^ ((row & 7u) << 4));
  }

  // prologue: stage tile 0 into buf 0
#pragma unroll
  for (int c = 0; c < 6; ++c)
    gll16(KhB + kOff[c], (char*)(&sK[0][0]) + (w * 6 + c) * 1024);
  __syncthreads();

  f4v acc[8][2] = {};
  float mrun[2] = {-3.0e38f, -3.0e38f};
  float lsum[2] = {0.f, 0.f};
  const int nt = 2 * (qb + 1);
  int cur = 0;
  for (int t = 0; t < nt; ++t) {
    const int k0 = t * 64;
    if (t + 1 < nt) {                   // prefetch next tile into other buffer
      const char* gb = KhB + (size_t)(t + 1) * (64 * 384);
      char* lb = (char*)(&sK[cur ^ 1][0]);
#pragma unroll
      for (int c = 0; c < 6; ++c)
        gll16(gb + kOff[c], lb + (w * 6 + c) * 1024);
    }
    if (k0 <= qw + 31) {                // wave-uniform causal skip
      const char* sKc = (const char*)(&sK[cur][0]);
      f4v s[4][2] = {};
#pragma unroll
      for (int T = 0; T < 4; ++T) {
        const int row = T * 16 + l15;
        const unsigned swz = (unsigned)((row & 7) << 4);
#pragma unroll
        for (int kc = 0; kc < 6; ++kc) {
          s8v kf = *reinterpret_cast<const s8v*>(
              sKc + row * 384 + (unsigned)((kc * 64 + lg * 16) ^ swz));
          s[T][0] = __builtin_amdgcn_mfma_f32_16x16x32_bf16(kf, qfr[0][kc], s[T][0], 0, 0, 0);
          s[T][1] = __builtin_amdgcn_mfma_f32_16x16x32_bf16(kf, qfr[1][kc], s[T][1], 0, 0, 0);
        }
      }
      const bool diag = (t >= 2 * qb);
      unsigned pk[4][2][2];
#pragma unroll
      for (int mq = 0; mq < 2; ++mq) {
        const int qlane = qw + mq * 16 + l15;
        if (diag) {
#pragma unroll
          for (int T = 0; T < 4; ++T)
#pragma unroll
            for (int r = 0; r < 4; ++r)
              if (k0 + T * 16 + lg * 4 + r > qlane) s[T][mq][r] = -1.0e30f;
        }
        float tmax = s[0][mq][0];
#pragma unroll
        for (int T = 0; T < 4; ++T)
#pragma unroll
          for (int r = 0; r < 4; ++r) tmax = fmaxf(tmax, s[T][mq][r]);
        tmax = fmaxf(tmax, __shfl_xor(tmax, 16, 64));
        tmax = fmaxf(tmax, __shfl_xor(tmax, 32, 64));
        const float mnew = fmaxf(mrun[mq], tmax);
        const float cf = __expf(mrun[mq] - mnew);
        mrun[mq] = mnew;
        float rs = 0.f;
#pragma unroll
        for (int T = 0; T < 4; ++T)
#pragma unroll
          for (int r = 0; r < 4; ++r) {
            float e = __expf(s[T][mq][r] - mnew);
            s[T][mq][r] = e;
            rs += e;
          }
        rs += __shfl_xor(rs, 16, 64);
        rs += __shfl_xor(rs, 32, 64);
        lsum[mq] = lsum[mq] * cf + rs;
#pragma unroll
        for (int dt = 0; dt < 8; ++dt)
#pragma unroll
          for (int r = 0; r < 4; ++r) acc[dt][mq][r] *= cf;
#pragma unroll
        for (int T = 0; T < 4; ++T) {
          pk[T][mq][0] = (unsigned)(unsigned short)f2bf(s[T][mq][0]) |
                         ((unsigned)(unsigned short)f2bf(s[T][mq][1]) << 16);
          pk[T][mq][1] = (unsigned)(unsigned short)f2bf(s[T][mq][2]) |
                         ((unsigned)(unsigned short)f2bf(s[T][mq][3]) << 16);
        }
      }
      // PV: B-frag word j2 of chunk c2 = pk[2c2+(lg>>1)][j2&1] from lane
      // l15 + 16*((lg&1)*2 + (j2>>1))  (derived + verified lane mapping)
#pragma unroll
      for (int c2 = 0; c2 < 2; ++c2) {
        union { unsigned u[4]; s8v v; } bb[2];
#pragma unroll
        for (int mq = 0; mq < 2; ++mq)
#pragma unroll
          for (int j2 = 0; j2 < 4; ++j2) {
            int src = l15 + ((l & 16) << 1) + ((j2 & 2) << 3);
            unsigned va = (unsigned)__shfl((int)pk[2 * c2][mq][j2 & 1], src, 64);
            unsigned vb = (unsigned)__shfl((int)pk[2 * c2 + 1][mq][j2 & 1], src, 64);
            bb[mq].u[j2] = (l & 32) ? vb : va;
          }
#pragma unroll
        for (int dt = 0; dt < 8; ++dt) {
          s8v vf = *reinterpret_cast<const s8v*>(
              &Vh[(size_t)(dt * 16 + l15) * S_ + k0 + c2 * 32 + lg * 8]);
          acc[dt][0] = __builtin_amdgcn_mfma_f32_16x16x32_bf16(vf, bb[0].v, acc[dt][0], 0, 0, 0);
          acc[dt][1] = __builtin_amdgcn_mfma_f32_16x16x32_bf16(vf, bb[1].v, acc[dt][1], 0, 0, 0);
        }
      }
    }
    __syncthreads();                    // drains prefetch (vmcnt0) + LDS reads
    cur ^= 1;
  }
  // epilogue: O[q][d], 64B-coalesced float4 stores
#pragma unroll
  for (int mq = 0; mq < 2; ++mq) {
    const float inv = 1.0f / lsum[mq];
    const int q = qw + mq * 16 + l15;
    float* ob = out + (((size_t)b * S_ + q) * H_ + h) * 128 + lg * 4;
#pragma unroll
    for (int dt = 0; dt < 8; ++dt) {
      float4 o4 = { acc[dt][mq][0] * inv, acc[dt][mq][1] * inv,
                    acc[dt][mq][2] * inv, acc[dt][mq][3] * inv };
      *reinterpret_cast<float4*>(ob + dt * 16) = o4;
    }
  }
}

// ---------------- launch ----------------
extern "C" void kernel_launch(void* const* d_in, const int* in_sizes, int n_in,
                              void* d_out, int out_size, void* d_ws, size_t ws_size,
                              hipStream_t stream) {
  const float* Q    = (const float*)d_in[0];
  const float* KV   = (const float*)d_in[1];
  const float* PE   = (const float*)d_in[2];
  const float* WUQ  = (const float*)d_in[3];
  const float* WUKV = (const float*)d_in[4];
  const float* cosb = (const float*)d_in[5];
  const float* sinb = (const float*)d_in[6];
  float* out = (float*)d_out;
  char* ws = (char*)d_ws;

  short* Qb    = (short*)(ws);                   // 4096*1536*2  = 12,582,912
  short* Wq    = (short*)(ws + 12582912);        // 6144*1536*2  = 18,874,368
  short* KVb   = (short*)(ws + 31457280);        // 4096*512*2   =  4,194,304
  short* Wkv   = (short*)(ws + 35651584);        // 8192*512*2   =  8,388,608
  short* qfull = (short*)(ws + 44040192);        // 4*32*1024*192*2 = 50,331,648
  short* kfull = (short*)(ws + 94371840);        // 50,331,648
  short* vtb   = (short*)(ws + 144703488);       // 4*32*128*1024*2 = 33,554,432

  convert_f32_bf16<<<6144, 256, 0, stream>>>(Q, Qb, 1572864);
  convert_f32_bf16<<<9216, 256, 0, stream>>>(WUQ, Wq, 2359296);
  convert_f32_bf16<<<2048, 256, 0, stream>>>(KV, KVb, 524288);
  convert_f32_bf16<<<4096, 256, 0, stream>>>(WUKV, Wkv, 1048576);

  gemm_q_kernel<<<1536, 256, 0, stream>>>(Qb, Wq, cosb, sinb, qfull);
  gemm_kv_kernel<<<2048, 256, 0, stream>>>(KVb, Wkv, kfull, vtb);
  kpe_kernel<<<4096, 64, 0, stream>>>(PE, cosb, sinb, kfull);

  attn_kernel<<<1024, 256, 0, stream>>>(qfull, kfull, vtb, out);
}